// Round 3
// baseline (102.022 us; speedup 1.0000x reference)
//
#include <hip/hip_runtime.h>

#define N_FEAT 128
#define ROWS   32      // rows per tile
#define TPB    256     // 4 waves; each wave owns 8 rows of the tile
#define GRID   1024    // 4 tiles per block (ntiles = 4096)

// DPP cross-lane add on the VALU pipe: v + dpp_perm(v). No LDS traffic.
template<int CTRL>
__device__ __forceinline__ float dpp_xadd(float v) {
    int t = __builtin_amdgcn_update_dpp(0, __float_as_int(v), CTRL, 0xF, 0xF, true);
    return v + __int_as_float(t);
}

// Full 64-lane sum entirely on VALU (DPP + gfx950 permlane*_swap).
__device__ __forceinline__ float wave_allsum(float v) {
    v = dpp_xadd<0xB1>(v);    // quad_perm [1,0,3,2]  == xor 1
    v = dpp_xadd<0x4E>(v);    // quad_perm [2,3,0,1]  == xor 2
    v = dpp_xadd<0x141>(v);   // row_half_mirror      == xor 4
    v = dpp_xadd<0x140>(v);   // row_mirror           == xor 8
#if __has_builtin(__builtin_amdgcn_permlane16_swap)
    {
        auto p = __builtin_amdgcn_permlane16_swap(__float_as_uint(v), __float_as_uint(v), false, false);
        v = __uint_as_float(p[0]) + __uint_as_float(p[1]);   // == xor 16
    }
#else
    v += __int_as_float(__builtin_amdgcn_ds_swizzle(__float_as_int(v), 0x401F));
#endif
    {
        auto p = __builtin_amdgcn_permlane32_swap(__float_as_uint(v), __float_as_uint(v), false, false);
        v = __uint_as_float(p[0]) + __uint_as_float(p[1]);   // == xor 32
    }
    return v;
}

__global__ __launch_bounds__(TPB, 4)
void spn_fused(const float* __restrict__ x,
               const float* __restrict__ means,
               const float* __restrict__ stds,
               const float* __restrict__ sumw,
               const int* __restrict__ perm,
               float* __restrict__ out, int n) {
    const float NHALF_LOG2E = -0.7213475204444817f;        // -0.5*log2(e)
    const float LN2      = 0.6931471805599453f;
    const float LOG2E    = 1.4426950408889634f;
    const float L2PI_L2E = 2.6514961294723187f;            // ln(2*pi)*log2(e)

    const int tid  = threadIdx.x;
    const int lane = tid & 63;
    const int wv   = tid >> 6;

    const int ntiles = n / ROWS;
    const int stride = gridDim.x;

    // ---- per-lane param fold, log2-domain (v_log/v_exp only, no libm) ----
    const int g  = lane;
    const int p0 = perm[2 * g], p1 = perm[2 * g + 1];
    float w2[3];
#pragma unroll
    for (int m = 0; m < 3; ++m) w2[m] = sumw[g * 3 + m] * LOG2E;
    const float mx2 = fmaxf(w2[0], fmaxf(w2[1], w2[2]));
    const float lse2 = mx2 + __builtin_amdgcn_logf(__builtin_amdgcn_exp2f(w2[0] - mx2)
                                                 + __builtin_amdgcn_exp2f(w2[1] - mx2)
                                                 + __builtin_amdgcn_exp2f(w2[2] - mx2));
    float nm0[3], is0[3], nm1[3], is1[3], C2[3];
#pragma unroll
    for (int m = 0; m < 3; ++m) {
        const float s0 = stds[p0 * 3 + m], mu0 = means[p0 * 3 + m];
        const float s1 = stds[p1 * 3 + m], mu1 = means[p1 * 3 + m];
        const float i0 = 1.0f / s0, i1 = 1.0f / s1;
        nm0[m] = mu0 * i0;  is0[m] = i0;
        nm1[m] = mu1 * i1;  is1[m] = i1;
        C2[m]  = (w2[m] - lse2) - __builtin_amdgcn_logf(s0)
                                - __builtin_amdgcn_logf(s1) - L2PI_L2E;
    }

    // per-wave row block base offset within a tile
    const float* xw = x + (size_t)wv * (8 * N_FEAT);

    // load THIS wave's 16 needed floats of tile t straight into registers.
    // Wave collectively consumes the full 4 KB row-block (perm is a permutation),
    // so cache lines are fully used -> HBM traffic = ideal 67 MB.
    auto load_tile = [&](int t, float* A, float* B) {
        const float* base = xw + (size_t)t * (ROWS * N_FEAT);
#pragma unroll
        for (int r = 0; r < 8; ++r) {
            A[r] = base[r * N_FEAT + p0];
            B[r] = base[r * N_FEAT + p1];
        }
    };

    auto compute_store = [&](const float* A, const float* B, int t) {
        float res[8];
#pragma unroll
        for (int r = 0; r < 8; ++r) {
            const float a = A[r];
            const float b = B[r];
            float v0, v1, v2;
            {
                float z0 = fmaf(a, is0[0], -nm0[0]);
                float z1 = fmaf(b, is1[0], -nm1[0]);
                v0 = fmaf(z0 * z0, NHALF_LOG2E, C2[0]);
                v0 = fmaf(z1 * z1, NHALF_LOG2E, v0);
            }
            {
                float z0 = fmaf(a, is0[1], -nm0[1]);
                float z1 = fmaf(b, is1[1], -nm1[1]);
                v1 = fmaf(z0 * z0, NHALF_LOG2E, C2[1]);
                v1 = fmaf(z1 * z1, NHALF_LOG2E, v1);
            }
            {
                float z0 = fmaf(a, is0[2], -nm0[2]);
                float z1 = fmaf(b, is1[2], -nm1[2]);
                v2 = fmaf(z0 * z0, NHALF_LOG2E, C2[2]);
                v2 = fmaf(z1 * z1, NHALF_LOG2E, v2);
            }
            float pmx = fmaxf(v0, fmaxf(v1, v2));
            float s = __builtin_amdgcn_exp2f(v0 - pmx)
                    + __builtin_amdgcn_exp2f(v1 - pmx)
                    + __builtin_amdgcn_exp2f(v2 - pmx);
            res[r] = pmx + __builtin_amdgcn_logf(s);   // v_log_f32 = log2
        }

#pragma unroll
        for (int r = 0; r < 8; ++r)
            res[r] = wave_allsum(res[r]);

        if (lane == 0) {
            float4* op = (float4*)(out + t * ROWS + wv * 8);
            op[0] = make_float4(res[0] * LN2, res[1] * LN2, res[2] * LN2, res[3] * LN2);
            op[1] = make_float4(res[4] * LN2, res[5] * LN2, res[6] * LN2, res[7] * LN2);
        }
    };

    // ---- register double-buffered pipeline, manually 2x-unrolled
    //      (all array indices compile-time constant -> stays in VGPRs) ----
    int t = blockIdx.x;
    if (t >= ntiles) return;

    float aA[8], bA[8], aB[8], bB[8];
    load_tile(t, aA, bA);
    while (true) {
        const int t1 = t + stride;
        if (t1 < ntiles) load_tile(t1, aB, bB);   // prefetch overlaps compute below
        compute_store(aA, bA, t);
        if (t1 >= ntiles) break;

        const int t2 = t1 + stride;
        if (t2 < ntiles) load_tile(t2, aA, bA);
        compute_store(aB, bB, t1);
        if (t2 >= ntiles) break;
        t = t2;
    }
}

extern "C" void kernel_launch(void* const* d_in, const int* in_sizes, int n_in,
                              void* d_out, int out_size, void* d_ws, size_t ws_size,
                              hipStream_t stream) {
    const float* x     = (const float*)d_in[0];
    const float* means = (const float*)d_in[1];
    const float* stds  = (const float*)d_in[2];
    const float* sumw  = (const float*)d_in[3];
    const int*   perm  = (const int*)d_in[4];
    float* out = (float*)d_out;
    int n = in_sizes[0] / N_FEAT;          // 131072 rows

    int ntiles = n / ROWS;                 // 4096
    int grid = GRID < ntiles ? GRID : (ntiles > 0 ? ntiles : 1);

    hipLaunchKernelGGL(spn_fused, dim3(grid), dim3(TPB), 0, stream,
                       x, means, stds, sumw, perm, out, n);
}

// Round 4
// 100.363 us; speedup vs baseline: 1.0165x; 1.0165x over previous
//
#include <hip/hip_runtime.h>

#define N_FEAT 128
#define ROWS   32      // rows per tile
#define TPB    256     // 4 waves; each wave owns 8 rows of the tile
#define GRID   1024    // 4 tiles per block (ntiles = 4096)

// DPP cross-lane add on the VALU pipe: v + dpp_perm(v).
template<int CTRL>
__device__ __forceinline__ float dpp_xadd(float v) {
    int t = __builtin_amdgcn_update_dpp(0, __float_as_int(v), CTRL, 0xF, 0xF, true);
    return v + __int_as_float(t);
}

// Full 64-lane sum on VALU (DPP + gfx950 permlane*_swap). Zero DS traffic.
__device__ __forceinline__ float wave_allsum(float v) {
    v = dpp_xadd<0xB1>(v);    // quad_perm [1,0,3,2]  == xor 1
    v = dpp_xadd<0x4E>(v);    // quad_perm [2,3,0,1]  == xor 2
    v = dpp_xadd<0x141>(v);   // row_half_mirror      == xor 4
    v = dpp_xadd<0x140>(v);   // row_mirror           == xor 8
#if __has_builtin(__builtin_amdgcn_permlane16_swap)
    {
        auto p = __builtin_amdgcn_permlane16_swap(__float_as_uint(v), __float_as_uint(v), false, false);
        v = __uint_as_float(p[0]) + __uint_as_float(p[1]);   // == xor 16
    }
#else
    v += __int_as_float(__builtin_amdgcn_ds_swizzle(__float_as_int(v), 0x401F));
#endif
    {
        auto p = __builtin_amdgcn_permlane32_swap(__float_as_uint(v), __float_as_uint(v), false, false);
        v = __uint_as_float(p[0]) + __uint_as_float(p[1]);   // == xor 32
    }
    return v;
}

__global__ __launch_bounds__(TPB, 4)
void spn_fused(const float* __restrict__ x,
               const float* __restrict__ means,
               const float* __restrict__ stds,
               const float* __restrict__ sumw,
               const int* __restrict__ perm,
               float* __restrict__ out, int n) {
    const float NHALF_LOG2E = -0.7213475204444817f;        // -0.5*log2(e)
    const float LN2      = 0.6931471805599453f;
    const float LOG2E    = 1.4426950408889634f;
    const float L2PI_L2E = 2.6514961294723187f;            // ln(2*pi)*log2(e)

    const int tid  = threadIdx.x;
    const int lane = tid & 63;
    const int wv   = tid >> 6;

    const int ntiles = n / ROWS;
    const int stride = gridDim.x;

    // ---- per-lane param fold, log2-domain ----
    const int g  = lane;
    const int p0 = perm[2 * g], p1 = perm[2 * g + 1];
    float w2[3];
#pragma unroll
    for (int m = 0; m < 3; ++m) w2[m] = sumw[g * 3 + m] * LOG2E;
    const float mx2 = fmaxf(w2[0], fmaxf(w2[1], w2[2]));
    const float lse2 = mx2 + __builtin_amdgcn_logf(__builtin_amdgcn_exp2f(w2[0] - mx2)
                                                 + __builtin_amdgcn_exp2f(w2[1] - mx2)
                                                 + __builtin_amdgcn_exp2f(w2[2] - mx2));
    float nm0[3], is0[3], nm1[3], is1[3], C2[3];
#pragma unroll
    for (int m = 0; m < 3; ++m) {
        const float s0 = stds[p0 * 3 + m], mu0 = means[p0 * 3 + m];
        const float s1 = stds[p1 * 3 + m], mu1 = means[p1 * 3 + m];
        const float i0 = 1.0f / s0, i1 = 1.0f / s1;
        nm0[m] = mu0 * i0;  is0[m] = i0;
        nm1[m] = mu1 * i1;  is1[m] = i1;
        C2[m]  = (w2[m] - lse2) - __builtin_amdgcn_logf(s0)
                                - __builtin_amdgcn_logf(s1) - L2PI_L2E;
    }

    // bpermute routing, loop-invariant: column p lives in lane p>>1, word p&1.
    const int idxA = (p0 >> 1) << 2;       // byte index = src_lane * 4
    const int idxB = (p1 >> 1) << 2;
    const bool selA = (p0 & 1) != 0;
    const bool selB = (p1 & 1) != 0;

    // lane l loads float2 {col 2l, col 2l+1}: one dwordx2 per row = 512 B
    // fully-coalesced per instruction. 8 instr/wave-tile (vs 128 scattered
    // transactions in the gather version).
    const float2* xf2 = (const float2*)x;
    const size_t waverow = (size_t)wv * 8;  // first row of this wave within tile

    auto load_tile = [&](int t, float2* L) {
        const size_t base = ((size_t)t * ROWS + waverow) * 64 + lane;
#pragma unroll
        for (int r = 0; r < 8; ++r)
            L[r] = xf2[base + (size_t)r * 64];
    };

    auto compute_store = [&](const float2* L, int t) {
        float res[8];
#pragma unroll
        for (int r = 0; r < 8; ++r) {
            const int lo = __float_as_int(L[r].x);
            const int hi = __float_as_int(L[r].y);
            const float aLo = __int_as_float(__builtin_amdgcn_ds_bpermute(idxA, lo));
            const float aHi = __int_as_float(__builtin_amdgcn_ds_bpermute(idxA, hi));
            const float bLo = __int_as_float(__builtin_amdgcn_ds_bpermute(idxB, lo));
            const float bHi = __int_as_float(__builtin_amdgcn_ds_bpermute(idxB, hi));
            const float a = selA ? aHi : aLo;
            const float b = selB ? bHi : bLo;

            float v0, v1, v2;
            {
                float z0 = fmaf(a, is0[0], -nm0[0]);
                float z1 = fmaf(b, is1[0], -nm1[0]);
                v0 = fmaf(z0 * z0, NHALF_LOG2E, C2[0]);
                v0 = fmaf(z1 * z1, NHALF_LOG2E, v0);
            }
            {
                float z0 = fmaf(a, is0[1], -nm0[1]);
                float z1 = fmaf(b, is1[1], -nm1[1]);
                v1 = fmaf(z0 * z0, NHALF_LOG2E, C2[1]);
                v1 = fmaf(z1 * z1, NHALF_LOG2E, v1);
            }
            {
                float z0 = fmaf(a, is0[2], -nm0[2]);
                float z1 = fmaf(b, is1[2], -nm1[2]);
                v2 = fmaf(z0 * z0, NHALF_LOG2E, C2[2]);
                v2 = fmaf(z1 * z1, NHALF_LOG2E, v2);
            }
            float pmx = fmaxf(v0, fmaxf(v1, v2));
            float s = __builtin_amdgcn_exp2f(v0 - pmx)
                    + __builtin_amdgcn_exp2f(v1 - pmx)
                    + __builtin_amdgcn_exp2f(v2 - pmx);
            res[r] = pmx + __builtin_amdgcn_logf(s);   // v_log_f32 = log2
        }

#pragma unroll
        for (int r = 0; r < 8; ++r)
            res[r] = wave_allsum(res[r]);

        if (lane == 0) {
            float4* op = (float4*)(out + t * ROWS + wv * 8);
            op[0] = make_float4(res[0] * LN2, res[1] * LN2, res[2] * LN2, res[3] * LN2);
            op[1] = make_float4(res[4] * LN2, res[5] * LN2, res[6] * LN2, res[7] * LN2);
        }
    };

    // ---- register double-buffered pipeline, manual 2x unroll
    //      (all indices compile-time -> everything stays in VGPRs) ----
    int t = blockIdx.x;
    if (t >= ntiles) return;

    float2 LA[8], LB[8];
    load_tile(t, LA);
    while (true) {
        const int t1 = t + stride;
        if (t1 < ntiles) load_tile(t1, LB);    // prefetch overlaps compute
        compute_store(LA, t);
        if (t1 >= ntiles) break;

        const int t2 = t1 + stride;
        if (t2 < ntiles) load_tile(t2, LA);
        compute_store(LB, t1);
        if (t2 >= ntiles) break;
        t = t2;
    }
}

extern "C" void kernel_launch(void* const* d_in, const int* in_sizes, int n_in,
                              void* d_out, int out_size, void* d_ws, size_t ws_size,
                              hipStream_t stream) {
    const float* x     = (const float*)d_in[0];
    const float* means = (const float*)d_in[1];
    const float* stds  = (const float*)d_in[2];
    const float* sumw  = (const float*)d_in[3];
    const int*   perm  = (const int*)d_in[4];
    float* out = (float*)d_out;
    int n = in_sizes[0] / N_FEAT;          // 131072 rows

    int ntiles = n / ROWS;                 // 4096
    int grid = GRID < ntiles ? GRID : (ntiles > 0 ? ntiles : 1);

    hipLaunchKernelGGL(spn_fused, dim3(grid), dim3(TPB), 0, stream,
                       x, means, stds, sumw, perm, out, n);
}